// Round 20
// baseline (272.193 us; speedup 1.0000x reference)
//
#include <hip/hip_runtime.h>

#define H_ 128
#define W_ 128
#define HW_ (H_ * W_)
#define B_ 4
#define CH2_ (2 * HW_)   // 32768 floats
#define NT_ 1024

// ---------------- ablation probes (write checksums into ws; overwritten later) ----

// Probe 1: exact event-stream access pattern of event_hist_kernel, nothing else.
__global__ __launch_bounds__(NT_, 4)
void probe_stream(const float* __restrict__ event_list, float* __restrict__ probe,
                  int nN, int bpb, int cs) {
    int tid = threadIdx.x;
    int b   = blockIdx.x / (bpb * 2);
    int rem = blockIdx.x - b * (bpb * 2);
    int j   = rem >> 1;
    const float4* evb = reinterpret_cast<const float4*>(event_list) + (size_t)b * nN;
    int start = j * cs, end = min(nN, start + cs);
    float acc = 0.0f;
    int i = start + tid;
    for (; i + 3 * NT_ < end; i += 4 * NT_) {
        float4 e0 = evb[i], e1 = evb[i + NT_], e2 = evb[i + 2 * NT_], e3 = evb[i + 3 * NT_];
        acc += e0.x + e0.y + e0.z + e0.w;
        acc += e1.x + e1.y + e1.z + e1.w;
        acc += e2.x + e2.y + e2.z + e2.w;
        acc += e3.x + e3.y + e3.z + e3.w;
    }
    for (; i < end; i += NT_) { float4 e = evb[i]; acc += e.x + e.y + e.z + e.w; }
    probe[(size_t)blockIdx.x * NT_ + tid] = acc;   // keep live
}

// Probe 2: stream + the exact divergent flow gathers (no LDS, no scatter).
__global__ __launch_bounds__(NT_, 4)
void probe_gather(const float* __restrict__ event_list, const float* __restrict__ flow,
                  float* __restrict__ probe, int nN, int bpb, int cs) {
    int tid = threadIdx.x;
    int b   = blockIdx.x / (bpb * 2);
    int rem = blockIdx.x - b * (bpb * 2);
    int j   = rem >> 1;
    const float* fb = flow + (size_t)b * CH2_;
    const float4* evb = reinterpret_cast<const float4*>(event_list) + (size_t)b * nN;
    int start = j * cs, end = min(nN, start + cs);
    float acc = 0.0f;
    int i = start + tid;
    for (; i + 3 * NT_ < end; i += 4 * NT_) {
        float4 ev[4];
        #pragma unroll
        for (int u = 0; u < 4; ++u) ev[u] = evb[i + u * NT_];
        #pragma unroll
        for (int u = 0; u < 4; ++u) {
            int py = __float2int_rn(ev[u].y);
            int px = __float2int_rn(ev[u].z);
            int pidx = max(0, min(HW_ - 1, py * W_ + px));
            acc += fb[pidx] + fb[HW_ + pidx] + ev[u].x + ev[u].w;
        }
    }
    for (; i < end; i += NT_) {
        float4 e = evb[i];
        int py = __float2int_rn(e.y);
        int px = __float2int_rn(e.z);
        int pidx = max(0, min(HW_ - 1, py * W_ + px));
        acc += fb[pidx] + fb[HW_ + pidx] + e.x + e.w;
    }
    probe[(size_t)blockIdx.x * NT_ + tid] = acc;   // keep live
}

// ---------------- real pipeline (unchanged from round 18, passed @ 193 µs) -------

__device__ __forceinline__ void scatter_one(float4 ev, int pol,
                                            float* __restrict__ hist,
                                            const float* __restrict__ fb) {
    bool mine = ((ev.w > 0.5f) ? 0 : 1) == pol;   // pol 0 = positive channel
    if (!mine) return;

    int py = __float2int_rn(ev.y);
    int px = __float2int_rn(ev.z);
    int pidx = max(0, min(HW_ - 1, py * W_ + px));
    float fx = fb[pidx];            // flow channel 0 (x)
    float fy = fb[HW_ + pidx];      // flow channel 1 (y)

    float rts = 1.0f - ev.x;        // (1 - ts)
    float wy = fmaf(rts, fy, ev.y); // warped y (flow ch1)
    float wx = fmaf(rts, fx, ev.z); // warped x (flow ch0)

    float tyf = floorf(wy), lxf = floorf(wx);
    float fyf = wy - tyf;
    float fxf = wx - lxf;
    int ity = (int)tyf, ilx = (int)lxf;

    float wr0 = 1.0f - fyf, wr1 = fyf;
    float wc0 = 1.0f - fxf, wc1 = fxf;

    bool y0 = (ity >= 0) & (ity < H_);
    bool y1 = (ity + 1 >= 0) & (ity + 1 < H_);
    bool x0 = (ilx >= 0) & (ilx < W_);
    bool x1 = (ilx + 1 >= 0) & (ilx + 1 < W_);

    if (y0 & x0) atomicAdd(hist + ity * W_ + ilx,           wr0 * wc0);
    if (y0 & x1) atomicAdd(hist + ity * W_ + ilx + 1,       wr0 * wc1);
    if (y1 & x0) atomicAdd(hist + (ity + 1) * W_ + ilx,     wr1 * wc0);
    if (y1 & x1) atomicAdd(hist + (ity + 1) * W_ + ilx + 1, wr1 * wc1);
}

__global__ __launch_bounds__(NT_, 8)
void event_hist_kernel(const float* __restrict__ event_list,
                       const float* __restrict__ flow,
                       float* __restrict__ ws,
                       int nN, int bpb, int cs) {
    __shared__ float hist[HW_];      // 64 KB
    int tid = threadIdx.x;
    int b   = blockIdx.x / (bpb * 2);
    int rem = blockIdx.x - b * (bpb * 2);
    int j   = rem >> 1;
    int pol = rem & 1;

    for (int i = tid; i < HW_; i += NT_) hist[i] = 0.0f;
    __syncthreads();

    const float* fb = flow + (size_t)b * CH2_;
    const float4* evb = reinterpret_cast<const float4*>(event_list) + (size_t)b * nN;
    int start = j * cs;
    int end = min(nN, start + cs);

    int i = start + tid;
    for (; i + 3 * NT_ < end; i += 4 * NT_) {
        float4 ev[4];
        #pragma unroll
        for (int u = 0; u < 4; ++u) ev[u] = evb[i + u * NT_];
        #pragma unroll
        for (int u = 0; u < 4; ++u) scatter_one(ev[u], pol, hist, fb);
    }
    for (; i < end; i += NT_) scatter_one(evb[i], pol, hist, fb);

    __syncthreads();
    float* wsb = ws + ((size_t)(b * bpb + j) * 2 + pol) * HW_;
    for (int i2 = tid; i2 < HW_ / 4; i2 += NT_)
        reinterpret_cast<float4*>(wsb)[i2] =
            reinterpret_cast<const float4*>(hist)[i2];
}

__global__ void reduce_kernel(const float* __restrict__ ws,
                              const float* __restrict__ flow,
                              const float* __restrict__ event_mask,
                              float* __restrict__ out, int bpb) {
    int idx = blockIdx.x * blockDim.x + threadIdx.x;
    if (idx >= B_ * CH2_) return;
    int b = idx / CH2_;
    int r = idx - b * CH2_;            // r = ch*HW + pix

    const float* base = ws + (size_t)b * bpb * CH2_ + r;
    float s = 0.0f;
    #pragma unroll 8
    for (int j = 0; j < bpb; ++j) s += base[(size_t)j * CH2_];

    int ch  = r / HW_;
    int pix = r - ch * HW_;
    float* ob = out + (size_t)b * 4 * HW_;
    ob[ch * HW_ + pix] = s;                          // iwe channel

    float m = event_mask[b * HW_ + pix];
    float f = flow[(size_t)b * CH2_ + r];
    ob[(2 + ch) * HW_ + pix] = f * m / (m + 1e-9f);  // avg_flow channel
}

extern "C" void kernel_launch(void* const* d_in, const int* in_sizes, int n_in,
                              void* d_out, int out_size, void* d_ws, size_t ws_size,
                              hipStream_t stream) {
    const float* flow       = (const float*)d_in[0];  // [B,2,H,W]
    const float* event_list = (const float*)d_in[1];  // [B,N,4]
    const float* event_mask = (const float*)d_in[3];  // [B,1,H,W]
    float* out = (float*)d_out;                       // [B,4,H,W]
    float* ws  = (float*)d_ws;

    int nN = in_sizes[1] / (B_ * 4);                  // events per batch

    int bpb = 64;
    while (bpb > 1 && (size_t)B_ * bpb * CH2_ * 4 > ws_size) bpb >>= 1;
    int cs = (nN + bpb - 1) / bpb;                    // events per block

    int grid = B_ * bpb * 2;

    // --- ablation probes (timing decomposition via rocprof per-dispatch dur) ---
    // They write checksums into ws; event_hist_kernel overwrites that region next.
    probe_stream<<<grid, NT_, 0, stream>>>(event_list, ws, nN, bpb, cs);
    probe_gather<<<grid, NT_, 0, stream>>>(event_list, flow, ws, nN, bpb, cs);

    // --- real pipeline (unchanged) ---
    event_hist_kernel<<<grid, NT_, 0, stream>>>(event_list, flow, ws, nN, bpb, cs);

    int n2 = B_ * CH2_;
    reduce_kernel<<<(n2 + 255) / 256, 256, 0, stream>>>(ws, flow, event_mask, out, bpb);
}